// Round 2
// baseline (3286.615 us; speedup 1.0000x reference)
//
#include <hip/hip_runtime.h>

// Net_39135742001869: S2VT video-caption LSTM (enc 80 + dec 39 steps), bf16 MFMA.
// R2: persistent-barrier recurrence (weights in VGPRs), bf16 A for all GEMMs.

typedef unsigned short u16;
typedef __attribute__((ext_vector_type(8))) short s8v;   // 8 x bf16 (as short)
typedef __attribute__((ext_vector_type(4))) float f4v;   // MFMA accumulator

#define VOC   6000
#define VOCP  6144        // padded to multiple of 256
#define CHUNK_M 3328      // 3 x 3328 = 9984 decode rows

__device__ __forceinline__ u16 f2b(float f) {
  unsigned u = __float_as_uint(f);
  unsigned r = (u + 0x7fffu + ((u >> 16) & 1u)) >> 16;   // RNE f32->bf16
  return (u16)r;
}
__device__ __forceinline__ float b2f(u16 u) {
  return __uint_as_float(((unsigned)u) << 16);
}
__device__ __forceinline__ float sigm(float x) { return 1.f / (1.f + __expf(-x)); }
__device__ __forceinline__ float tanh_f(float x) {
  float e = __expf(-2.f * fabsf(x));
  float t = (1.f - e) / (1.f + e);
  return x >= 0.f ? t : -t;
}

// ---------------- f32 -> bf16 elementwise conversion (8 elems/thread) ------------------
__global__ __launch_bounds__(256) void conv_f2b(const float* __restrict__ src,
                                                u16* __restrict__ dst, long n) {
  long stride = (long)gridDim.x * 2048;
  for (long i = ((long)blockIdx.x * 256 + threadIdx.x) * 8; i < n; i += stride) {
    float4 a = *(const float4*)(src + i);
    float4 b = *(const float4*)(src + i + 4);
    unsigned w0 = (unsigned)f2b(a.x) | ((unsigned)f2b(a.y) << 16);
    unsigned w1 = (unsigned)f2b(a.z) | ((unsigned)f2b(a.w) << 16);
    unsigned w2 = (unsigned)f2b(b.x) | ((unsigned)f2b(b.y) << 16);
    unsigned w3 = (unsigned)f2b(b.z) | ((unsigned)f2b(b.w) << 16);
    *(int4*)(dst + i) = make_int4((int)w0, (int)w1, (int)w2, (int)w3);
  }
}

// ---------------- weight pack (f32 -> bf16, strided slice + zero pad rows) -------------
__global__ void pack_bf16(u16* __restrict__ dst, int dld, int doff,
                          const float* __restrict__ src, int sld, int soff,
                          int Wc, int R, int Rsrc) {
  int i = blockIdx.x * 256 + threadIdx.x;
  if (i >= Wc * R) return;
  int r = i / Wc, c = i - r * Wc;
  float v = (r < Rsrc) ? src[(size_t)r * sld + soff + c] : 0.f;
  dst[(size_t)r * dld + doff + c] = f2b(v);
}

__global__ void bias_setup(const float* __restrict__ bi1, const float* __restrict__ bh1,
                           const float* __restrict__ bi2, const float* __restrict__ bh2,
                           const float* __restrict__ bo,
                           float* __restrict__ b1s, float* __restrict__ b2s,
                           float* __restrict__ bop) {
  int i = blockIdx.x * 256 + threadIdx.x;
  if (i < 1024) { b1s[i] = bi1[i] + bh1[i]; b2s[i] = bi2[i] + bh2[i]; }
  if (i < VOCP) bop[i] = (i < VOC) ? bo[i] : 0.f;
}

// ---------------- targets = argmax(caption_one_hot[b, d+1, :]) -------------------------
__global__ __launch_bounds__(256) void argmax_kernel(const float* __restrict__ coh,
                                                     int* __restrict__ tgt) {
  const int d = blockIdx.x >> 8;       // 0..38
  const int b = blockIdx.x & 255;
  const float4* row = (const float4*)(coh + ((size_t)b * 40 + (d + 1)) * VOC);
  float best = -3.4e38f; int bi = 0;
  for (int v = threadIdx.x; v < VOC / 4; v += 256) {
    float4 x = row[v];
    float vals[4] = {x.x, x.y, x.z, x.w};
#pragma unroll
    for (int j = 0; j < 4; ++j)
      if (vals[j] > best) { best = vals[j]; bi = v * 4 + j; }
  }
#pragma unroll
  for (int o = 1; o < 64; o <<= 1) {
    float ov = __shfl_xor(best, o);
    int   oi = __shfl_xor(bi, o);
    if (ov > best || (ov == best && oi < bi)) { best = ov; bi = oi; }
  }
  __shared__ float sv[4]; __shared__ int si[4];
  if ((threadIdx.x & 63) == 0) { sv[threadIdx.x >> 6] = best; si[threadIdx.x >> 6] = bi; }
  __syncthreads();
  if (threadIdx.x == 0) {
    for (int i = 1; i < 4; ++i)
      if (sv[i] > best || (sv[i] == best && si[i] < bi)) { best = sv[i]; bi = si[i]; }
    tgt[blockIdx.x] = bi;              // layout [d][b]
  }
}

// ---------------- GEMM: C[M][ldc] = A_bf16[M][K] * Bw_bf16[N][K]^T + bias --------------
// grid = (M/128, N/256); K multiple of 64. OB=1 -> bf16 out, OB=0 -> f32 out.
template <int OB>
__global__ __launch_bounds__(256) void gemm_bb(
    const u16* __restrict__ A, const u16* __restrict__ Bw,
    const float* __restrict__ bias, void* __restrict__ Cout,
    int K, int ldc)
{
  const int m0 = blockIdx.x * 128;
  const int n0 = blockIdx.y * 256;
  const int tid = threadIdx.x;
  const int lane = tid & 63;
  const int wid = tid >> 6;
  const int wm = wid >> 1, wn = wid & 1;
  const int fr = lane & 15;
  const int fk = (lane >> 4) * 8;
  const int rq = lane >> 4;

  __shared__ u16 As[128][72];   // pad: stride 144B -> 2-way-only bank aliasing
  __shared__ u16 Bs[256][72];
  f4v acc[4][8] = {};

  const int ar = tid >> 1, ac = (tid & 1) * 32;
  int4 av[4], bv[8];
  {
    const u16* ap = A + (size_t)(m0 + ar) * K + ac;
    const u16* bp = Bw + (size_t)(n0 + tid) * K;
#pragma unroll
    for (int v = 0; v < 4; ++v) av[v] = *(const int4*)(ap + v * 8);
#pragma unroll
    for (int v = 0; v < 8; ++v) bv[v] = *(const int4*)(bp + v * 8);
  }
#pragma unroll 1
  for (int k0 = 0; k0 < K; k0 += 64) {
    __syncthreads();
#pragma unroll
    for (int v = 0; v < 4; ++v) *(int4*)&As[ar][ac + v * 8] = av[v];
#pragma unroll
    for (int v = 0; v < 8; ++v) *(int4*)&Bs[tid][v * 8] = bv[v];
    __syncthreads();
    if (k0 + 64 < K) {
      const u16* ap = A + (size_t)(m0 + ar) * K + k0 + 64 + ac;
      const u16* bp = Bw + (size_t)(n0 + tid) * K + k0 + 64;
#pragma unroll
      for (int v = 0; v < 4; ++v) av[v] = *(const int4*)(ap + v * 8);
#pragma unroll
      for (int v = 0; v < 8; ++v) bv[v] = *(const int4*)(bp + v * 8);
    }
#pragma unroll
    for (int ks = 0; ks < 2; ++ks) {
      const int kb = ks * 32 + fk;
      s8v a[4], b[8];
#pragma unroll
      for (int i = 0; i < 4; ++i) a[i] = *(const s8v*)&As[wm * 64 + i * 16 + fr][kb];
#pragma unroll
      for (int j = 0; j < 8; ++j) b[j] = *(const s8v*)&Bs[wn * 128 + j * 16 + fr][kb];
#pragma unroll
      for (int i = 0; i < 4; ++i)
#pragma unroll
        for (int j = 0; j < 8; ++j)
          acc[i][j] = __builtin_amdgcn_mfma_f32_16x16x32_bf16(a[i], b[j], acc[i][j], 0, 0, 0);
    }
  }
#pragma unroll
  for (int j = 0; j < 8; ++j) {
    const int n = n0 + wn * 128 + j * 16 + fr;
    const float bz = bias[n];
#pragma unroll
    for (int i = 0; i < 4; ++i) {
      const int rb = m0 + wm * 64 + i * 16 + rq * 4;
#pragma unroll
      for (int r = 0; r < 4; ++r) {
        float vout = acc[i][j][r] + bz;
        if (OB) ((u16*)Cout)[(size_t)(rb + r) * ldc + n] = f2b(vout);
        else    ((float*)Cout)[(size_t)(rb + r) * ldc + n] = vout;
      }
    }
  }
}

// ---------------- persistent recurrence: 128 blocks, atomic grid barrier per round -----
__device__ __forceinline__ void gbar(unsigned* bar, unsigned target) {
  __syncthreads();
  if (threadIdx.x == 0) {
    __threadfence();
    __hip_atomic_fetch_add(bar, 1u, __ATOMIC_RELEASE, __HIP_MEMORY_SCOPE_AGENT);
    while (__hip_atomic_load(bar, __ATOMIC_RELAXED, __HIP_MEMORY_SCOPE_AGENT) < target) {
      __builtin_amdgcn_s_sleep(2);
    }
    __threadfence();
  }
  __syncthreads();
}

// Blocks 0..63: LSTM1(t) for t in [0,118]. Blocks 64..127: LSTM2(t-1) for t in [1,119].
// hcat: 2 banks of [256 batch][512] bf16 = [h1 | h2]. Round t reads bank (t+1)&1, writes t&1.
// All weights held in VGPRs (preloaded once). Cell state c held in VGPRs.
__global__ __launch_bounds__(256, 1) void recur_kernel(
    const u16* __restrict__ X1,       // [b*80+t][1024] bf16, bias folded
    const u16* __restrict__ Xc,       // [b*40+d][1024] bf16, bias folded
    const float* __restrict__ b1sum, const float* __restrict__ b2sum,
    const u16* __restrict__ Whh1,     // [1024][256] bf16
    const u16* __restrict__ Wcat2,    // [1024][512] bf16 = [W_ih2[:,256:] | W_hh2]
    u16* __restrict__ hcat,
    u16* __restrict__ H2dec,          // [39*256][256] bf16
    unsigned* __restrict__ bar)
{
  const int tid = threadIdx.x;
  const int lane = tid & 63;
  const int w = tid >> 6;
  const int fr = lane & 15;
  const int fk = (lane >> 4) * 8;
  const int rq = lane >> 4;
  const bool p2 = blockIdx.x >= 64;
  const int bb = p2 ? (int)blockIdx.x - 64 : (int)blockIdx.x;
  const int bm = bb >> 4;
  const int bh = bb & 15;
  const int hd = bh * 16 + fr;
  const int rowA = bm * 64 + w * 16 + fr;
  const int batbase = bm * 64 + w * 16 + rq * 4;

  // ---- one-time: weight fragments into registers ----
  s8v wv[64];
  float br[4];
  if (!p2) {
#pragma unroll
    for (int q = 0; q < 4; ++q) {
      br[q] = b1sum[q * 256 + hd];
#pragma unroll
      for (int kk = 0; kk < 8; ++kk)
        wv[q * 8 + kk] =
            *(const s8v*)(Whh1 + (size_t)(q * 256 + bh * 16 + fr) * 256 + kk * 32 + fk);
    }
  } else {
#pragma unroll
    for (int q = 0; q < 4; ++q) {
      br[q] = b2sum[q * 256 + hd];
#pragma unroll
      for (int kk = 0; kk < 16; ++kk)
        wv[q * 16 + kk] =
            *(const s8v*)(Wcat2 + (size_t)(q * 256 + bh * 16 + fr) * 512 + kk * 32 + fk);
    }
  }
  float creg[4] = {0.f, 0.f, 0.f, 0.f};

#pragma unroll 1
  for (int t = 0; t < 120; ++t) {
    const u16* hr = hcat + (size_t)((t + 1) & 1) * (256 * 512);
    u16* hw = hcat + (size_t)(t & 1) * (256 * 512);
    if (!p2) {
      if (t <= 118) {
        // gate addend (X or bias) first, so loads overlap MFMAs
        float ga[4][4];
        if (t < 80) {
#pragma unroll
          for (int r = 0; r < 4; ++r) {
            const u16* xp = X1 + ((size_t)(batbase + r) * 80 + t) * 1024;
#pragma unroll
            for (int q = 0; q < 4; ++q) ga[r][q] = b2f(xp[q * 256 + hd]);
          }
        } else {
#pragma unroll
          for (int r = 0; r < 4; ++r)
#pragma unroll
            for (int q = 0; q < 4; ++q) ga[r][q] = br[q];
        }
        f4v acc[4] = {};
        const u16* arow = hr + (size_t)rowA * 512;
#pragma unroll
        for (int kk = 0; kk < 8; ++kk) {
          s8v a = *(const s8v*)(arow + kk * 32 + fk);
#pragma unroll
          for (int q = 0; q < 4; ++q)
            acc[q] = __builtin_amdgcn_mfma_f32_16x16x32_bf16(a, wv[q * 8 + kk], acc[q], 0, 0, 0);
        }
#pragma unroll
        for (int r = 0; r < 4; ++r) {
          const int bat = batbase + r;
          float g0 = acc[0][r] + ga[r][0], g1 = acc[1][r] + ga[r][1];
          float g2 = acc[2][r] + ga[r][2], g3 = acc[3][r] + ga[r][3];
          float cn = sigm(g1) * creg[r] + sigm(g0) * tanh_f(g2);
          float h = sigm(g3) * tanh_f(cn);
          creg[r] = cn;
          hw[(size_t)bat * 512 + hd] = f2b(h);
        }
      }
    } else {
      if (t >= 1) {
        const int s = t - 1;
        float ga[4][4];
        if (s >= 80) {
#pragma unroll
          for (int r = 0; r < 4; ++r) {
            const u16* xp = Xc + ((size_t)(batbase + r) * 40 + (s - 80)) * 1024;
#pragma unroll
            for (int q = 0; q < 4; ++q) ga[r][q] = b2f(xp[q * 256 + hd]);
          }
        } else {
#pragma unroll
          for (int r = 0; r < 4; ++r)
#pragma unroll
            for (int q = 0; q < 4; ++q) ga[r][q] = br[q];
        }
        f4v acc[4] = {};
        const u16* arow = hr + (size_t)rowA * 512;     // [h1(s) | h2(s-1)]
#pragma unroll
        for (int kk = 0; kk < 16; ++kk) {
          s8v a = *(const s8v*)(arow + kk * 32 + fk);
#pragma unroll
          for (int q = 0; q < 4; ++q)
            acc[q] = __builtin_amdgcn_mfma_f32_16x16x32_bf16(a, wv[q * 16 + kk], acc[q], 0, 0, 0);
        }
#pragma unroll
        for (int r = 0; r < 4; ++r) {
          const int bat = batbase + r;
          float g0 = acc[0][r] + ga[r][0], g1 = acc[1][r] + ga[r][1];
          float g2 = acc[2][r] + ga[r][2], g3 = acc[3][r] + ga[r][3];
          float cn = sigm(g1) * creg[r] + sigm(g0) * tanh_f(g2);
          float h = sigm(g3) * tanh_f(cn);
          creg[r] = cn;
          u16 hb = f2b(h);
          hw[(size_t)bat * 512 + 256 + hd] = hb;
          if (s >= 80) H2dec[((size_t)(s - 80) * 256 + bat) * 256 + hd] = hb;
        }
      }
    }
    if (t < 119) gbar(bar, 128u * (unsigned)(t + 1));
  }
}

// ---------------- per-row logsumexp NLL over the padded logits -------------------------
__global__ __launch_bounds__(256) void nll_kernel(const float* __restrict__ logits,
                                                  const int* __restrict__ tgt,
                                                  float* __restrict__ rowloss, int rg0) {
  const int rl = blockIdx.x;
  const float* row = logits + (size_t)rl * VOCP;
  const float4* row4 = (const float4*)row;
  const int tid = threadIdx.x;
  float mx = -3.4e38f;
  for (int v = tid; v < VOC / 4; v += 256) {
    float4 x = row4[v];
    mx = fmaxf(mx, fmaxf(fmaxf(x.x, x.y), fmaxf(x.z, x.w)));
  }
#pragma unroll
  for (int o = 1; o < 64; o <<= 1) mx = fmaxf(mx, __shfl_xor(mx, o));
  __shared__ float s1[4];
  if ((tid & 63) == 0) s1[tid >> 6] = mx;
  __syncthreads();
  mx = fmaxf(fmaxf(s1[0], s1[1]), fmaxf(s1[2], s1[3]));
  float sm = 0.f;
  for (int v = tid; v < VOC / 4; v += 256) {
    float4 x = row4[v];
    sm += __expf(x.x - mx) + __expf(x.y - mx) + __expf(x.z - mx) + __expf(x.w - mx);
  }
#pragma unroll
  for (int o = 1; o < 64; o <<= 1) sm += __shfl_xor(sm, o);
  __shared__ float s2[4];
  if ((tid & 63) == 0) s2[tid >> 6] = sm;
  __syncthreads();
  if (tid == 0) {
    float tot = s2[0] + s2[1] + s2[2] + s2[3];
    rowloss[rg0 + rl] = mx + __logf(tot) - row[tgt[rg0 + rl]];
  }
}

__global__ __launch_bounds__(256) void final_kernel(const float* __restrict__ rowloss,
                                                    float* __restrict__ out) {
  float s = 0.f;
  for (int n = threadIdx.x; n < 9984; n += 256) s += rowloss[n];
#pragma unroll
  for (int o = 1; o < 64; o <<= 1) s += __shfl_xor(s, o);
  __shared__ float sr[4];
  if ((threadIdx.x & 63) == 0) sr[threadIdx.x >> 6] = s;
  __syncthreads();
  if (threadIdx.x == 0) out[0] = (sr[0] + sr[1] + sr[2] + sr[3]) * (1.f / 256.f);
}

// ---------------------------------------------------------------------------------------
extern "C" void kernel_launch(void* const* d_in, const int* in_sizes, int n_in,
                              void* d_out, int out_size, void* d_ws, size_t ws_size,
                              hipStream_t stream) {
  const float* feat    = (const float*)d_in[0];
  const float* caption = (const float*)d_in[1];
  const float* coh     = (const float*)d_in[2];
  const float* W_ih1   = (const float*)d_in[3];
  const float* W_hh1   = (const float*)d_in[4];
  const float* b_ih1   = (const float*)d_in[5];
  const float* b_hh1   = (const float*)d_in[6];
  const float* W_ih2   = (const float*)d_in[7];
  const float* W_hh2   = (const float*)d_in[8];
  const float* b_ih2   = (const float*)d_in[9];
  const float* b_hh2   = (const float*)d_in[10];
  const float* W_out   = (const float*)d_in[11];
  const float* b_out   = (const float*)d_in[12];

  char* p = (char*)d_ws;
  auto take = [&](size_t bytes) { char* r = p; p += (bytes + 255) & ~(size_t)255; return r; };
  // persistent region (~77 MB)
  u16* X1b    = (u16*)take(20480ull * 1024 * 2);   // feat @ W_ih1^T + b1sum (bf16)
  u16* Xcb    = (u16*)take(10240ull * 1024 * 2);   // caption @ W_ih2[:,:256]^T + b2sum (bf16)
  u16* Wih1b  = (u16*)take(1024ull * 4096 * 2);
  u16* Whh1b  = (u16*)take(1024ull * 256 * 2);
  u16* Wih2ab = (u16*)take(1024ull * 256 * 2);
  u16* Wcat2b = (u16*)take(1024ull * 512 * 2);
  u16* Woutb  = (u16*)take((size_t)VOCP * 256 * 2);
  u16* hcat   = (u16*)take(2ull * 256 * 512 * 2);
  float* b1sum = (float*)take(1024 * 4);
  float* b2sum = (float*)take(1024 * 4);
  float* boutp = (float*)take(VOCP * 4);
  int*   tgt   = (int*)take(9984 * 4);
  float* rowloss = (float*)take(9984 * 4);
  unsigned* bar  = (unsigned*)take(256);
  // union region (~89 MB): {featb chunk + capb} then {H2dec + logits}
  char* uni = p;
  u16* featb = (u16*)uni;                                       // 10240 x 4096 bf16 (83.9 MB)
  u16* capb  = (u16*)(uni + 10240ull * 4096 * 2);               // 10240 x 256 bf16 (5.2 MB)
  u16* H2dec = (u16*)uni;                                       // 9984 x 256 bf16 (5.1 MB)
  float* logits = (float*)(uni + ((9984ull * 256 * 2 + 255) & ~(size_t)255)); // 81.8 MB

  hipMemsetAsync(hcat, 0, 2ull * 256 * 512 * 2, stream);
  hipMemsetAsync(bar, 0, 4, stream);

  bias_setup<<<dim3(24), dim3(256), 0, stream>>>(b_ih1, b_hh1, b_ih2, b_hh2, b_out,
                                                 b1sum, b2sum, boutp);
  auto pack = [&](u16* dst, int dld, int doff, const float* src, int sld, int soff,
                  int Wc, int R, int Rs) {
    int tot = Wc * R;
    pack_bf16<<<dim3((tot + 255) / 256), dim3(256), 0, stream>>>(dst, dld, doff, src, sld, soff,
                                                                 Wc, R, Rs);
  };
  pack(Wih1b, 4096, 0, W_ih1, 4096, 0, 4096, 1024, 1024);
  pack(Whh1b, 256, 0, W_hh1, 256, 0, 256, 1024, 1024);
  pack(Wih2ab, 256, 0, W_ih2, 512, 0, 256, 1024, 1024);     // W_ih2[:, :256]
  pack(Wcat2b, 512, 0, W_ih2, 512, 256, 256, 1024, 1024);   // W_ih2[:, 256:]
  pack(Wcat2b, 512, 256, W_hh2, 256, 0, 256, 1024, 1024);   // W_hh2
  pack(Woutb, 256, 0, W_out, 256, 0, 256, VOCP, VOC);       // zero-padded rows

  argmax_kernel<<<dim3(39 * 256), dim3(256), 0, stream>>>(coh, tgt);

  // caption -> bf16, then Xc = capb @ Wih2a^T + b2sum
  conv_f2b<<<dim3(2048), dim3(256), 0, stream>>>(caption, capb, 10240L * 256);
  gemm_bb<1><<<dim3(80, 4), dim3(256), 0, stream>>>(capb, Wih2ab, b2sum, Xcb, 256, 1024);

  // feat -> bf16 in 2 chunks (keeps union region small, keeps A L3-resident), X1 GEMM
  for (int c = 0; c < 2; ++c) {
    conv_f2b<<<dim3(2048), dim3(256), 0, stream>>>(feat + (size_t)c * 10240 * 4096, featb,
                                                   10240L * 4096);
    gemm_bb<1><<<dim3(80, 4), dim3(256), 0, stream>>>(featb, Wih1b, b1sum,
                                                      X1b + (size_t)c * 10240 * 1024,
                                                      4096, 1024);
  }

  // whole 119-step double-LSTM recurrence in ONE kernel (128 blocks, atomic barrier)
  recur_kernel<<<dim3(128), dim3(256), 0, stream>>>(X1b, Xcb, b1sum, b2sum,
                                                    Whh1b, Wcat2b, hcat, H2dec, bar);

  for (int ch = 0; ch < 3; ++ch) {
    gemm_bb<0><<<dim3(CHUNK_M / 128, VOCP / 256), dim3(256), 0, stream>>>(
        H2dec + (size_t)ch * CHUNK_M * 256, Woutb, boutp, logits, 256, VOCP);
    nll_kernel<<<dim3(CHUNK_M), dim3(256), 0, stream>>>(logits, tgt, rowloss, ch * CHUNK_M);
  }
  final_kernel<<<dim3(1), dim3(256), 0, stream>>>(rowloss, (float*)d_out);
}

// Round 3
// 3251.688 us; speedup vs baseline: 1.0107x; 1.0107x over previous
//
#include <hip/hip_runtime.h>

// Net_39135742001869: S2VT video-caption LSTM (enc 80 + dec 39 steps), bf16 MFMA.
// R3: fence-free persistent recurrence (sc1 relaxed atomics, LDS weights), fused NLL.

typedef unsigned short u16;
typedef unsigned int u32;
typedef unsigned long long u64;
typedef __attribute__((ext_vector_type(8))) short s8v;   // 8 x bf16 (as short)
typedef __attribute__((ext_vector_type(4))) float f4v;   // MFMA accumulator

#define VOC   6000
#define VOCP  6144        // padded to multiple of 256

__device__ __forceinline__ u16 f2b(float f) {
  unsigned u = __float_as_uint(f);
  unsigned r = (u + 0x7fffu + ((u >> 16) & 1u)) >> 16;   // RNE f32->bf16
  return (u16)r;
}
__device__ __forceinline__ float b2f(u16 u) {
  return __uint_as_float(((unsigned)u) << 16);
}
__device__ __forceinline__ float sigm(float x) { return 1.f / (1.f + __expf(-x)); }
__device__ __forceinline__ float tanh_f(float x) {
  float e = __expf(-2.f * fabsf(x));
  float t = (1.f - e) / (1.f + e);
  return x >= 0.f ? t : -t;
}

// ---------------- f32 -> bf16 elementwise conversion (8 elems/thread) ------------------
__global__ __launch_bounds__(256) void conv_f2b(const float* __restrict__ src,
                                                u16* __restrict__ dst, long n) {
  long stride = (long)gridDim.x * 2048;
  for (long i = ((long)blockIdx.x * 256 + threadIdx.x) * 8; i < n; i += stride) {
    float4 a = *(const float4*)(src + i);
    float4 b = *(const float4*)(src + i + 4);
    unsigned w0 = (unsigned)f2b(a.x) | ((unsigned)f2b(a.y) << 16);
    unsigned w1 = (unsigned)f2b(a.z) | ((unsigned)f2b(a.w) << 16);
    unsigned w2 = (unsigned)f2b(b.x) | ((unsigned)f2b(b.y) << 16);
    unsigned w3 = (unsigned)f2b(b.z) | ((unsigned)f2b(b.w) << 16);
    *(int4*)(dst + i) = make_int4((int)w0, (int)w1, (int)w2, (int)w3);
  }
}

// ---------------- weight pack (f32 -> bf16, strided slice + zero pad rows) -------------
__global__ void pack_bf16(u16* __restrict__ dst, int dld, int doff,
                          const float* __restrict__ src, int sld, int soff,
                          int Wc, int R, int Rsrc) {
  int i = blockIdx.x * 256 + threadIdx.x;
  if (i >= Wc * R) return;
  int r = i / Wc, c = i - r * Wc;
  float v = (r < Rsrc) ? src[(size_t)r * sld + soff + c] : 0.f;
  dst[(size_t)r * dld + doff + c] = f2b(v);
}

__global__ void bias_setup(const float* __restrict__ bi1, const float* __restrict__ bh1,
                           const float* __restrict__ bi2, const float* __restrict__ bh2,
                           const float* __restrict__ bo,
                           float* __restrict__ b1s, float* __restrict__ b2s,
                           float* __restrict__ bop) {
  int i = blockIdx.x * 256 + threadIdx.x;
  if (i < 1024) { b1s[i] = bi1[i] + bh1[i]; b2s[i] = bi2[i] + bh2[i]; }
  if (i < VOCP) bop[i] = (i < VOC) ? bo[i] : -1e30f;   // -inf-ish pad: excluded from LSE
}

// ---------------- targets = argmax(caption_one_hot[b, d+1, :]) -------------------------
__global__ __launch_bounds__(256) void argmax_kernel(const float* __restrict__ coh,
                                                     int* __restrict__ tgt) {
  const int d = blockIdx.x >> 8;       // 0..38
  const int b = blockIdx.x & 255;
  const float4* row = (const float4*)(coh + ((size_t)b * 40 + (d + 1)) * VOC);
  float best = -3.4e38f; int bi = 0;
  for (int v = threadIdx.x; v < VOC / 4; v += 256) {
    float4 x = row[v];
    float vals[4] = {x.x, x.y, x.z, x.w};
#pragma unroll
    for (int j = 0; j < 4; ++j)
      if (vals[j] > best) { best = vals[j]; bi = v * 4 + j; }
  }
#pragma unroll
  for (int o = 1; o < 64; o <<= 1) {
    float ov = __shfl_xor(best, o);
    int   oi = __shfl_xor(bi, o);
    if (ov > best || (ov == best && oi < bi)) { best = ov; bi = oi; }
  }
  __shared__ float sv[4]; __shared__ int si[4];
  if ((threadIdx.x & 63) == 0) { sv[threadIdx.x >> 6] = best; si[threadIdx.x >> 6] = bi; }
  __syncthreads();
  if (threadIdx.x == 0) {
    for (int i = 1; i < 4; ++i)
      if (sv[i] > best || (sv[i] == best && si[i] < bi)) { best = sv[i]; bi = si[i]; }
    tgt[blockIdx.x] = bi;              // layout [d][b]
  }
}

// ---------------- GEMM: acc = A_bf16[M][K] * Bw_bf16[N][K]^T (+bias), 3 epilogues ------
// grid = (M/128, N/256); K multiple of 64.
// MODE 0: X1t  (bf16 out, row m=b*80+t -> X[(t*256+b)*1024 + n])
// MODE 1: Xct  (bf16 out, row m=b*40+d -> X[(d*256+b)*1024 + n])
// MODE 2: fused NLL partials: per (row, n-half-tile) write (max, expsum) + target logit
template <int MODE>
__global__ __launch_bounds__(256) void gemm_bb(
    const u16* __restrict__ A, const u16* __restrict__ Bw,
    const float* __restrict__ bias, void* __restrict__ out0,
    float* __restrict__ ps, float* __restrict__ tgtlog, const int* __restrict__ tgt,
    int K, int moff)
{
  const int m0 = blockIdx.x * 128;
  const int n0 = blockIdx.y * 256;
  const int tid = threadIdx.x;
  const int lane = tid & 63;
  const int wid = tid >> 6;
  const int wm = wid >> 1, wn = wid & 1;
  const int fr = lane & 15;
  const int fk = (lane >> 4) * 8;
  const int rq = lane >> 4;

  __shared__ u16 As[128][72];   // pad: stride 144B -> benign 2-way bank aliasing
  __shared__ u16 Bs[256][72];
  f4v acc[4][8] = {};

  const int ar = tid >> 1, ac = (tid & 1) * 32;
  int4 av[4], bv[8];
  {
    const u16* ap = A + (size_t)(m0 + ar) * K + ac;
    const u16* bp = Bw + (size_t)(n0 + tid) * K;
#pragma unroll
    for (int v = 0; v < 4; ++v) av[v] = *(const int4*)(ap + v * 8);
#pragma unroll
    for (int v = 0; v < 8; ++v) bv[v] = *(const int4*)(bp + v * 8);
  }
#pragma unroll 1
  for (int k0 = 0; k0 < K; k0 += 64) {
    __syncthreads();
#pragma unroll
    for (int v = 0; v < 4; ++v) *(int4*)&As[ar][ac + v * 8] = av[v];
#pragma unroll
    for (int v = 0; v < 8; ++v) *(int4*)&Bs[tid][v * 8] = bv[v];
    __syncthreads();
    if (k0 + 64 < K) {
      const u16* ap = A + (size_t)(m0 + ar) * K + k0 + 64 + ac;
      const u16* bp = Bw + (size_t)(n0 + tid) * K + k0 + 64;
#pragma unroll
      for (int v = 0; v < 4; ++v) av[v] = *(const int4*)(ap + v * 8);
#pragma unroll
      for (int v = 0; v < 8; ++v) bv[v] = *(const int4*)(bp + v * 8);
    }
#pragma unroll
    for (int ks = 0; ks < 2; ++ks) {
      const int kb = ks * 32 + fk;
      s8v a[4], b[8];
#pragma unroll
      for (int i = 0; i < 4; ++i) a[i] = *(const s8v*)&As[wm * 64 + i * 16 + fr][kb];
#pragma unroll
      for (int j = 0; j < 8; ++j) b[j] = *(const s8v*)&Bs[wn * 128 + j * 16 + fr][kb];
#pragma unroll
      for (int i = 0; i < 4; ++i)
#pragma unroll
        for (int j = 0; j < 8; ++j)
          acc[i][j] = __builtin_amdgcn_mfma_f32_16x16x32_bf16(a[i], b[j], acc[i][j], 0, 0, 0);
    }
  }

  float bz[8];
#pragma unroll
  for (int j = 0; j < 8; ++j) bz[j] = bias[n0 + wn * 128 + j * 16 + fr];

  if (MODE == 2) {
    const int tile = blockIdx.y * 2 + wn;
    float* pm = (float*)out0;
#pragma unroll
    for (int i = 0; i < 4; ++i) {
#pragma unroll
      for (int r = 0; r < 4; ++r) {
        const int row = m0 + wm * 64 + i * 16 + rq * 4 + r;
        const int tg = tgt[row];
        float vj[8]; float m = -1e30f;
#pragma unroll
        for (int j = 0; j < 8; ++j) {
          const int n = n0 + wn * 128 + j * 16 + fr;
          float v = acc[i][j][r] + bz[j];
          vj[j] = v;
          m = fmaxf(m, v);
          if (n == tg) tgtlog[row] = v;
        }
#pragma unroll
        for (int o = 1; o < 16; o <<= 1) m = fmaxf(m, __shfl_xor(m, o));
        float s = 0.f;
#pragma unroll
        for (int j = 0; j < 8; ++j) s += __expf(vj[j] - m);
#pragma unroll
        for (int o = 1; o < 16; o <<= 1) s += __shfl_xor(s, o);
        if (fr == 0) { pm[(size_t)row * 48 + tile] = m; ps[(size_t)row * 48 + tile] = s; }
      }
    }
  } else {
    u16* X = (u16*)out0;
    const int TT = (MODE == 0) ? 80 : 40;
#pragma unroll
    for (int i = 0; i < 4; ++i) {
#pragma unroll
      for (int r = 0; r < 4; ++r) {
        const int m = moff + m0 + wm * 64 + i * 16 + rq * 4 + r;
        const int bat = m / TT;
        const int tt = m - bat * TT;
        u16* crow = X + ((size_t)tt * 256 + bat) * 1024;
#pragma unroll
        for (int j = 0; j < 8; ++j) {
          const int n = n0 + wn * 128 + j * 16 + fr;
          crow[n] = f2b(acc[i][j][r] + bz[j]);
        }
      }
    }
  }
}

// ---------------- persistent recurrence --------------------------------------------------
// 128 blocks x 128 threads (2 waves). Blocks 0..63: LSTM1(t), t in [0,118].
// Blocks 64..127: LSTM2(t-1). hcat: 2 banks [256 bat][512] bf16 = [h1|h2];
// round t reads bank (t+1)&1, writes bank t&1, via sc1 (agent-relaxed) loads/stores.
// Weights live in LDS (XOR-swizzled). Barrier: relaxed fetch_add + relaxed poll (no fences).
__global__ __launch_bounds__(128, 1) void recur_kernel(
    const u16* __restrict__ X1t,      // [80][256][1024] bf16, bias folded
    const u16* __restrict__ Xct,      // [40][256][1024] bf16, bias folded
    const float* __restrict__ b1sum, const float* __restrict__ b2sum,
    const u16* __restrict__ Whh1,     // [1024][256] bf16
    const u16* __restrict__ Wcat2,    // [1024][512] bf16 = [W_ih2[:,256:] | W_hh2]
    u16* __restrict__ hcat,
    u16* __restrict__ H2dec,          // [39*256][256] bf16
    unsigned* __restrict__ bar)
{
  __shared__ u16 wlds[64 * 512];      // 64 KiB: this block's weight slice, swizzled
  const int tid = threadIdx.x;
  const int lane = tid & 63;
  const int w = tid >> 6;             // wave 0..1
  const int fr = lane & 15;
  const int fk8 = lane >> 4;          // k-quarter 0..3
  const int fk = fk8 * 8;
  const int rq = lane >> 4;
  const bool p2 = blockIdx.x >= 64;
  const int bb = p2 ? (int)blockIdx.x - 64 : (int)blockIdx.x;
  const int bm = bb >> 4;             // batch quarter
  const int bh = bb & 15;             // h-dim 16-col tile
  const int hd = bh * 16 + fr;
  const int LD = p2 ? 512 : 256;
  const int KK = p2 ? 16 : 8;

  // ---- one-time: weight slice -> LDS (rows l=q*16+rr <-> global q*256+bh*16+rr),
  //      16B-granule XOR swizzle: c8 ^= (row&7)  (kills stride-LD bank conflicts)
  {
    const u16* Wsrc = p2 ? Wcat2 : Whh1;
    const int C8 = LD / 8;
    for (int idx = tid; idx < 64 * C8; idx += 128) {
      int l = idx / C8, c8 = idx - l * C8;
      int gr = (l >> 4) * 256 + bh * 16 + (l & 15);
      int4 v = *(const int4*)(Wsrc + (size_t)gr * LD + c8 * 8);
      *(int4*)&wlds[l * LD + ((c8 ^ (l & 7)) * 8)] = v;
    }
  }
  float br4[4];
  {
    const float* bsrc = p2 ? b2sum : b1sum;
#pragma unroll
    for (int q = 0; q < 4; ++q) br4[q] = bsrc[q * 256 + hd];
  }
  __syncthreads();

  float creg[2][4] = {};

#pragma unroll 1
  for (int t = 0; t < 120; ++t) {
    const u16* hr = hcat + (size_t)((t + 1) & 1) * (256 * 512);
    u16* hw = hcat + (size_t)(t & 1) * (256 * 512);
    const bool act = p2 ? (t >= 1) : (t <= 118);
    if (act) {
      const int s = p2 ? t - 1 : t;
      // ---- A fragments: h rows via sc1 loads (bypass non-coherent L2) ----
      s8v a[2][16];
#pragma unroll
      for (int i = 0; i < 2; ++i) {
        const int row = bm * 64 + w * 32 + i * 16 + fr;
        const u16* arow = hr + (size_t)row * 512;
#pragma unroll
        for (int kk = 0; kk < 16; ++kk) {
          if (kk < KK) {
            union { u64 q[2]; s8v v; } u;
            const u64* src = (const u64*)(arow + kk * 32 + fk);
            u.q[0] = __hip_atomic_load(src,     __ATOMIC_RELAXED, __HIP_MEMORY_SCOPE_AGENT);
            u.q[1] = __hip_atomic_load(src + 1, __ATOMIC_RELAXED, __HIP_MEMORY_SCOPE_AGENT);
            a[i][kk] = u.v;
          }
        }
      }
      // ---- gate addend (X or bias) ----
      const bool useX = p2 ? (s >= 80) : (s < 80);
      float ga[2][4][4];
      if (useX) {
        const u16* Xb = p2 ? (Xct + (size_t)(s - 80) * 256 * 1024)
                           : (X1t + (size_t)s * 256 * 1024);
#pragma unroll
        for (int i = 0; i < 2; ++i)
#pragma unroll
          for (int r = 0; r < 4; ++r) {
            const int bat = bm * 64 + w * 32 + i * 16 + rq * 4 + r;
            const u16* xp = Xb + (size_t)bat * 1024;
#pragma unroll
            for (int q = 0; q < 4; ++q) ga[i][r][q] = b2f(xp[q * 256 + hd]);
          }
      } else {
#pragma unroll
        for (int i = 0; i < 2; ++i)
#pragma unroll
          for (int r = 0; r < 4; ++r)
#pragma unroll
            for (int q = 0; q < 4; ++q) ga[i][r][q] = br4[q];
      }
      // ---- MFMAs (B fragments streamed from LDS; shared across the 2 row-tiles) ----
      f4v acc[2][4] = {};
#pragma unroll
      for (int kk = 0; kk < 16; ++kk) {
        if (kk < KK) {
#pragma unroll
          for (int q = 0; q < 4; ++q) {
            s8v b = *(const s8v*)&wlds[(q * 16 + fr) * LD + (((kk * 4 + fk8) ^ (fr & 7)) * 8)];
#pragma unroll
            for (int i = 0; i < 2; ++i)
              acc[i][q] = __builtin_amdgcn_mfma_f32_16x16x32_bf16(a[i][kk], b, acc[i][q], 0, 0, 0);
          }
        }
      }
      // ---- cell update + h store (paired bf16 -> one u32 sc1 store per even lane) ----
      const int hcol = p2 ? 256 : 0;
#pragma unroll
      for (int i = 0; i < 2; ++i) {
#pragma unroll
        for (int r = 0; r < 4; ++r) {
          const int bat = bm * 64 + w * 32 + i * 16 + rq * 4 + r;
          float g0 = acc[i][0][r] + ga[i][r][0], g1 = acc[i][1][r] + ga[i][r][1];
          float g2 = acc[i][2][r] + ga[i][r][2], g3 = acc[i][3][r] + ga[i][r][3];
          float cn = sigm(g1) * creg[i][r] + sigm(g0) * tanh_f(g2);
          float h = sigm(g3) * tanh_f(cn);
          creg[i][r] = cn;
          unsigned hb = f2b(h);
          unsigned ob = (unsigned)__shfl_xor((int)hb, 1);
          if ((fr & 1) == 0) {
            unsigned word = hb | (ob << 16);
            __hip_atomic_store((u32*)(hw + (size_t)bat * 512 + hcol + hd), word,
                               __ATOMIC_RELAXED, __HIP_MEMORY_SCOPE_AGENT);
            if (p2 && s >= 80)
              *(u32*)(H2dec + ((size_t)(s - 80) * 256 + bat) * 256 + hd) = word;
          }
        }
      }
    }
    // ---- fence-free grid barrier (relaxed; sc1 data already globally visible) ----
    if (t < 119) {
      __syncthreads();   // drains vmcnt(0) per wave: all sc1 stores complete
      if (tid == 0) {
        __hip_atomic_fetch_add(bar, 1u, __ATOMIC_RELAXED, __HIP_MEMORY_SCOPE_AGENT);
        const unsigned tgtv = 128u * (unsigned)(t + 1);
        while (__hip_atomic_load(bar, __ATOMIC_RELAXED, __HIP_MEMORY_SCOPE_AGENT) < tgtv)
          __builtin_amdgcn_s_sleep(1);
      }
      __syncthreads();
    }
  }
}

// ---------------- combine per-tile LSE partials -> per-row NLL -------------------------
__global__ __launch_bounds__(256) void nll_combine(const float* __restrict__ pm,
                                                   const float* __restrict__ ps,
                                                   const float* __restrict__ tgtlog,
                                                   float* __restrict__ rowloss) {
  int row = blockIdx.x * 256 + threadIdx.x;
  if (row >= 9984) return;
  const float* pmr = pm + (size_t)row * 48;
  const float* psr = ps + (size_t)row * 48;
  float M = -1e30f;
#pragma unroll
  for (int t = 0; t < 48; ++t) M = fmaxf(M, pmr[t]);
  float S = 0.f;
#pragma unroll
  for (int t = 0; t < 48; ++t) S += psr[t] * __expf(pmr[t] - M);
  rowloss[row] = M + __logf(S) - tgtlog[row];
}

__global__ __launch_bounds__(256) void final_kernel(const float* __restrict__ rowloss,
                                                    float* __restrict__ out) {
  float s = 0.f;
  for (int n = threadIdx.x; n < 9984; n += 256) s += rowloss[n];
#pragma unroll
  for (int o = 1; o < 64; o <<= 1) s += __shfl_xor(s, o);
  __shared__ float sr[4];
  if ((threadIdx.x & 63) == 0) sr[threadIdx.x >> 6] = s;
  __syncthreads();
  if (threadIdx.x == 0) out[0] = (sr[0] + sr[1] + sr[2] + sr[3]) * (1.f / 256.f);
}

// ---------------------------------------------------------------------------------------
extern "C" void kernel_launch(void* const* d_in, const int* in_sizes, int n_in,
                              void* d_out, int out_size, void* d_ws, size_t ws_size,
                              hipStream_t stream) {
  const float* feat    = (const float*)d_in[0];
  const float* caption = (const float*)d_in[1];
  const float* coh     = (const float*)d_in[2];
  const float* W_ih1   = (const float*)d_in[3];
  const float* W_hh1   = (const float*)d_in[4];
  const float* b_ih1   = (const float*)d_in[5];
  const float* b_hh1   = (const float*)d_in[6];
  const float* W_ih2   = (const float*)d_in[7];
  const float* W_hh2   = (const float*)d_in[8];
  const float* b_ih2   = (const float*)d_in[9];
  const float* b_hh2   = (const float*)d_in[10];
  const float* W_out   = (const float*)d_in[11];
  const float* b_out   = (const float*)d_in[12];

  char* p = (char*)d_ws;
  auto take = [&](size_t bytes) { char* r = p; p += (bytes + 255) & ~(size_t)255; return r; };
  // persistent region
  u16* X1t    = (u16*)take(80ull * 256 * 1024 * 2);    // 41.9 MB, time-major
  u16* Xct    = (u16*)take(40ull * 256 * 1024 * 2);    // 21.0 MB, time-major
  u16* Wih1b  = (u16*)take(1024ull * 4096 * 2);
  u16* Whh1b  = (u16*)take(1024ull * 256 * 2);
  u16* Wih2ab = (u16*)take(1024ull * 256 * 2);
  u16* Wcat2b = (u16*)take(1024ull * 512 * 2);
  u16* Woutb  = (u16*)take((size_t)VOCP * 256 * 2);
  u16* hcat   = (u16*)take(2ull * 256 * 512 * 2);
  float* b1sum = (float*)take(1024 * 4);
  float* b2sum = (float*)take(1024 * 4);
  float* boutp = (float*)take(VOCP * 4);
  int*   tgt   = (int*)take(9984 * 4);
  float* tgtlog = (float*)take(9984 * 4);
  float* pm    = (float*)take(9984ull * 48 * 4);
  float* ps    = (float*)take(9984ull * 48 * 4);
  float* rowloss = (float*)take(9984 * 4);
  unsigned* bar  = (unsigned*)take(256);
  // union region: {featb chunk (83.9) + capb (5.2)} before recurrence, {H2dec (5.1)} after
  char* uni = p;
  u16* featb = (u16*)uni;
  u16* capb  = (u16*)(uni + 10240ull * 4096 * 2);
  u16* H2dec = (u16*)uni;

  hipMemsetAsync(hcat, 0, 2ull * 256 * 512 * 2, stream);
  hipMemsetAsync(bar, 0, 4, stream);

  bias_setup<<<dim3(24), dim3(256), 0, stream>>>(b_ih1, b_hh1, b_ih2, b_hh2, b_out,
                                                 b1sum, b2sum, boutp);
  auto pack = [&](u16* dst, int dld, int doff, const float* src, int sld, int soff,
                  int Wc, int R, int Rs) {
    int tot = Wc * R;
    pack_bf16<<<dim3((tot + 255) / 256), dim3(256), 0, stream>>>(dst, dld, doff, src, sld, soff,
                                                                 Wc, R, Rs);
  };
  pack(Wih1b, 4096, 0, W_ih1, 4096, 0, 4096, 1024, 1024);
  pack(Whh1b, 256, 0, W_hh1, 256, 0, 256, 1024, 1024);
  pack(Wih2ab, 256, 0, W_ih2, 512, 0, 256, 1024, 1024);     // W_ih2[:, :256]
  pack(Wcat2b, 512, 0, W_ih2, 512, 256, 256, 1024, 1024);   // W_ih2[:, 256:]
  pack(Wcat2b, 512, 256, W_hh2, 256, 0, 256, 1024, 1024);   // W_hh2
  pack(Woutb, 256, 0, W_out, 256, 0, 256, VOCP, VOC);       // zero-padded rows

  argmax_kernel<<<dim3(39 * 256), dim3(256), 0, stream>>>(coh, tgt);

  // caption -> bf16, Xct = capb @ Wih2a^T + b2sum   (time-major epilogue)
  conv_f2b<<<dim3(2048), dim3(256), 0, stream>>>(caption, capb, 10240L * 256);
  gemm_bb<1><<<dim3(80, 4), dim3(256), 0, stream>>>(capb, Wih2ab, b2sum, Xct,
                                                    nullptr, nullptr, nullptr, 256, 0);

  // feat -> bf16 (2 chunks), X1t = featb @ Wih1^T + b1sum   (time-major epilogue)
  for (int c = 0; c < 2; ++c) {
    conv_f2b<<<dim3(2048), dim3(256), 0, stream>>>(feat + (size_t)c * 10240 * 4096, featb,
                                                   10240L * 4096);
    gemm_bb<0><<<dim3(80, 4), dim3(256), 0, stream>>>(featb, Wih1b, b1sum, X1t,
                                                      nullptr, nullptr, nullptr, 4096,
                                                      c * 10240);
  }

  // whole 119-step double-LSTM recurrence in ONE persistent kernel
  recur_kernel<<<dim3(128), dim3(128), 0, stream>>>(X1t, Xct, b1sum, b2sum,
                                                    Whh1b, Wcat2b, hcat, H2dec, bar);

  // logits GEMM with fused per-tile LSE partials + target-logit extraction
  gemm_bb<2><<<dim3(78, 24), dim3(256), 0, stream>>>(H2dec, Woutb, boutp, pm,
                                                     ps, tgtlog, tgt, 256, 0);
  nll_combine<<<dim3(39), dim3(256), 0, stream>>>(pm, ps, tgtlog, rowloss);
  final_kernel<<<dim3(1), dim3(256), 0, stream>>>(rowloss, (float*)d_out);
}

// Round 4
// 2413.264 us; speedup vs baseline: 1.3619x; 1.3474x over previous
//
#include <hip/hip_runtime.h>

// Net_39135742001869: S2VT video-caption LSTM (enc 80 + dec 39 steps), bf16 MFMA.
// R4: barrier-free recurrence — single-writer watermark flags + h history buffers.

typedef unsigned short u16;
typedef unsigned int u32;
typedef unsigned long long u64;
typedef __attribute__((ext_vector_type(8))) short s8v;   // 8 x bf16 (as short)
typedef __attribute__((ext_vector_type(4))) float f4v;   // MFMA accumulator

#define VOC   6000
#define VOCP  6144        // padded to multiple of 256

__device__ __forceinline__ u16 f2b(float f) {
  unsigned u = __float_as_uint(f);
  unsigned r = (u + 0x7fffu + ((u >> 16) & 1u)) >> 16;   // RNE f32->bf16
  return (u16)r;
}
__device__ __forceinline__ float b2f(u16 u) {
  return __uint_as_float(((unsigned)u) << 16);
}
__device__ __forceinline__ float sigm(float x) { return 1.f / (1.f + __expf(-x)); }
__device__ __forceinline__ float tanh_f(float x) {
  float e = __expf(-2.f * fabsf(x));
  float t = (1.f - e) / (1.f + e);
  return x >= 0.f ? t : -t;
}

// ---------------- f32 -> bf16 elementwise conversion (8 elems/thread) ------------------
__global__ __launch_bounds__(256) void conv_f2b(const float* __restrict__ src,
                                                u16* __restrict__ dst, long n) {
  long stride = (long)gridDim.x * 2048;
  for (long i = ((long)blockIdx.x * 256 + threadIdx.x) * 8; i < n; i += stride) {
    float4 a = *(const float4*)(src + i);
    float4 b = *(const float4*)(src + i + 4);
    unsigned w0 = (unsigned)f2b(a.x) | ((unsigned)f2b(a.y) << 16);
    unsigned w1 = (unsigned)f2b(a.z) | ((unsigned)f2b(a.w) << 16);
    unsigned w2 = (unsigned)f2b(b.x) | ((unsigned)f2b(b.y) << 16);
    unsigned w3 = (unsigned)f2b(b.z) | ((unsigned)f2b(b.w) << 16);
    *(int4*)(dst + i) = make_int4((int)w0, (int)w1, (int)w2, (int)w3);
  }
}

// ---------------- weight pack (f32 -> bf16, strided slice + zero pad rows) -------------
__global__ void pack_bf16(u16* __restrict__ dst, int dld, int doff,
                          const float* __restrict__ src, int sld, int soff,
                          int Wc, int R, int Rsrc) {
  int i = blockIdx.x * 256 + threadIdx.x;
  if (i >= Wc * R) return;
  int r = i / Wc, c = i - r * Wc;
  float v = (r < Rsrc) ? src[(size_t)r * sld + soff + c] : 0.f;
  dst[(size_t)r * dld + doff + c] = f2b(v);
}

__global__ void bias_setup(const float* __restrict__ bi1, const float* __restrict__ bh1,
                           const float* __restrict__ bi2, const float* __restrict__ bh2,
                           const float* __restrict__ bo,
                           float* __restrict__ b1s, float* __restrict__ b2s,
                           float* __restrict__ bop) {
  int i = blockIdx.x * 256 + threadIdx.x;
  if (i < 1024) { b1s[i] = bi1[i] + bh1[i]; b2s[i] = bi2[i] + bh2[i]; }
  if (i < VOCP) bop[i] = (i < VOC) ? bo[i] : -1e30f;   // -inf-ish pad: excluded from LSE
}

// ---------------- targets = argmax(caption_one_hot[b, d+1, :]) -------------------------
__global__ __launch_bounds__(256) void argmax_kernel(const float* __restrict__ coh,
                                                     int* __restrict__ tgt) {
  const int d = blockIdx.x >> 8;       // 0..38
  const int b = blockIdx.x & 255;
  const float4* row = (const float4*)(coh + ((size_t)b * 40 + (d + 1)) * VOC);
  float best = -3.4e38f; int bi = 0;
  for (int v = threadIdx.x; v < VOC / 4; v += 256) {
    float4 x = row[v];
    float vals[4] = {x.x, x.y, x.z, x.w};
#pragma unroll
    for (int j = 0; j < 4; ++j)
      if (vals[j] > best) { best = vals[j]; bi = v * 4 + j; }
  }
#pragma unroll
  for (int o = 1; o < 64; o <<= 1) {
    float ov = __shfl_xor(best, o);
    int   oi = __shfl_xor(bi, o);
    if (ov > best || (ov == best && oi < bi)) { best = ov; bi = oi; }
  }
  __shared__ float sv[4]; __shared__ int si[4];
  if ((threadIdx.x & 63) == 0) { sv[threadIdx.x >> 6] = best; si[threadIdx.x >> 6] = bi; }
  __syncthreads();
  if (threadIdx.x == 0) {
    for (int i = 1; i < 4; ++i)
      if (sv[i] > best || (sv[i] == best && si[i] < bi)) { best = sv[i]; bi = si[i]; }
    tgt[blockIdx.x] = bi;              // layout [d][b]
  }
}

// ---------------- GEMM: acc = A_bf16[M][K] * Bw_bf16[N][K]^T (+bias), 3 epilogues ------
// grid = (M/128, N/256); K multiple of 64.
// MODE 0: X1t  (bf16 out, row m=b*80+t -> X[(t*256+b)*1024 + n])
// MODE 1: Xct  (bf16 out, row m=b*40+d -> X[(d*256+b)*1024 + n])
// MODE 2: fused NLL partials: per (row, n-half-tile) write (max, expsum) + target logit
template <int MODE>
__global__ __launch_bounds__(256) void gemm_bb(
    const u16* __restrict__ A, const u16* __restrict__ Bw,
    const float* __restrict__ bias, void* __restrict__ out0,
    float* __restrict__ ps, float* __restrict__ tgtlog, const int* __restrict__ tgt,
    int K, int moff)
{
  const int m0 = blockIdx.x * 128;
  const int n0 = blockIdx.y * 256;
  const int tid = threadIdx.x;
  const int lane = tid & 63;
  const int wid = tid >> 6;
  const int wm = wid >> 1, wn = wid & 1;
  const int fr = lane & 15;
  const int fk = (lane >> 4) * 8;
  const int rq = lane >> 4;

  __shared__ u16 As[128][72];   // pad: stride 144B -> benign 2-way bank aliasing
  __shared__ u16 Bs[256][72];
  f4v acc[4][8] = {};

  const int ar = tid >> 1, ac = (tid & 1) * 32;
  int4 av[4], bv[8];
  {
    const u16* ap = A + (size_t)(m0 + ar) * K + ac;
    const u16* bp = Bw + (size_t)(n0 + tid) * K;
#pragma unroll
    for (int v = 0; v < 4; ++v) av[v] = *(const int4*)(ap + v * 8);
#pragma unroll
    for (int v = 0; v < 8; ++v) bv[v] = *(const int4*)(bp + v * 8);
  }
#pragma unroll 1
  for (int k0 = 0; k0 < K; k0 += 64) {
    __syncthreads();
#pragma unroll
    for (int v = 0; v < 4; ++v) *(int4*)&As[ar][ac + v * 8] = av[v];
#pragma unroll
    for (int v = 0; v < 8; ++v) *(int4*)&Bs[tid][v * 8] = bv[v];
    __syncthreads();
    if (k0 + 64 < K) {
      const u16* ap = A + (size_t)(m0 + ar) * K + k0 + 64 + ac;
      const u16* bp = Bw + (size_t)(n0 + tid) * K + k0 + 64;
#pragma unroll
      for (int v = 0; v < 4; ++v) av[v] = *(const int4*)(ap + v * 8);
#pragma unroll
      for (int v = 0; v < 8; ++v) bv[v] = *(const int4*)(bp + v * 8);
    }
#pragma unroll
    for (int ks = 0; ks < 2; ++ks) {
      const int kb = ks * 32 + fk;
      s8v a[4], b[8];
#pragma unroll
      for (int i = 0; i < 4; ++i) a[i] = *(const s8v*)&As[wm * 64 + i * 16 + fr][kb];
#pragma unroll
      for (int j = 0; j < 8; ++j) b[j] = *(const s8v*)&Bs[wn * 128 + j * 16 + fr][kb];
#pragma unroll
      for (int i = 0; i < 4; ++i)
#pragma unroll
        for (int j = 0; j < 8; ++j)
          acc[i][j] = __builtin_amdgcn_mfma_f32_16x16x32_bf16(a[i], b[j], acc[i][j], 0, 0, 0);
    }
  }

  float bz[8];
#pragma unroll
  for (int j = 0; j < 8; ++j) bz[j] = bias[n0 + wn * 128 + j * 16 + fr];

  if (MODE == 2) {
    const int tile = blockIdx.y * 2 + wn;
    float* pm = (float*)out0;
#pragma unroll
    for (int i = 0; i < 4; ++i) {
#pragma unroll
      for (int r = 0; r < 4; ++r) {
        const int row = m0 + wm * 64 + i * 16 + rq * 4 + r;
        const int tg = tgt[row];
        float vj[8]; float m = -1e30f;
#pragma unroll
        for (int j = 0; j < 8; ++j) {
          const int n = n0 + wn * 128 + j * 16 + fr;
          float v = acc[i][j][r] + bz[j];
          vj[j] = v;
          m = fmaxf(m, v);
          if (n == tg) tgtlog[row] = v;
        }
#pragma unroll
        for (int o = 1; o < 16; o <<= 1) m = fmaxf(m, __shfl_xor(m, o));
        float s = 0.f;
#pragma unroll
        for (int j = 0; j < 8; ++j) s += __expf(vj[j] - m);
#pragma unroll
        for (int o = 1; o < 16; o <<= 1) s += __shfl_xor(s, o);
        if (fr == 0) { pm[(size_t)row * 48 + tile] = m; ps[(size_t)row * 48 + tile] = s; }
      }
    }
  } else {
    u16* X = (u16*)out0;
    const int TT = (MODE == 0) ? 80 : 40;
#pragma unroll
    for (int i = 0; i < 4; ++i) {
#pragma unroll
      for (int r = 0; r < 4; ++r) {
        const int m = moff + m0 + wm * 64 + i * 16 + rq * 4 + r;
        const int bat = m / TT;
        const int tt = m - bat * TT;
        u16* crow = X + ((size_t)tt * 256 + bat) * 1024;
#pragma unroll
        for (int j = 0; j < 8; ++j) {
          const int n = n0 + wn * 128 + j * 16 + fr;
          crow[n] = f2b(acc[i][j][r] + bz[j]);
        }
      }
    }
  }
}

// ---------------- barrier-free persistent recurrence ------------------------------------
// 128 blocks x 128 threads. Blocks 0..63: phase1 (LSTM1), 64..127: phase2 (LSTM2).
// Block (bm 0..3, bh 0..15) owns batch quarter bm (64 rows) x h-cols [bh*16, bh*16+16).
// History buffers h1hist/h2hist[120][256][256] bf16; slot s+1 = h(s); slot 0 = zeros.
// Producer: sc1-store h slice -> drain vmcnt -> relaxed flag store f[bm*16+bh] = s+1.
// Consumer: poll one 64B flag line (16 lanes, read-only; no RMW serialization).
// Phase1 step s waits f1[bm][*] >= s; phase2 step s waits f1[bm][*] >= s+1, f2[bm][*] >= s.
__global__ __launch_bounds__(128, 1) void recur_kernel(
    const u16* __restrict__ X1t,      // [80][256][1024] bf16, bias folded
    const u16* __restrict__ Xct,      // [40][256][1024] bf16, bias folded
    const float* __restrict__ b1sum, const float* __restrict__ b2sum,
    const u16* __restrict__ Whh1,     // [1024][256] bf16
    const u16* __restrict__ Wcat2,    // [1024][512] bf16 = [W_ih2[:,256:] | W_hh2]
    u16* __restrict__ h1hist,         // [120][256][256] bf16
    u16* __restrict__ h2hist,         // [120][256][256] bf16 (slots 81.. = H2dec)
    u32* __restrict__ f1, u32* __restrict__ f2)
{
  __shared__ u16 wlds[64 * 512];      // weight slice, rotation-swizzled
  const int tid = threadIdx.x;
  const int lane = tid & 63;
  const int w = tid >> 6;             // wave 0..1
  const int fr = lane & 15;
  const int fk8 = lane >> 4;          // k-quarter 0..3
  const int fk = fk8 * 8;
  const int rq = lane >> 4;
  const bool p2 = blockIdx.x >= 64;
  const int bb = p2 ? (int)blockIdx.x - 64 : (int)blockIdx.x;
  const int bm = bb >> 4;             // batch quarter
  const int bh = bb & 15;             // h-dim 16-col tile
  const int hd = bh * 16 + fr;
  const int LD = p2 ? 512 : 256;
  const int C8m = (p2 ? 64 : 32) - 1; // 16B-granule index mask per row
  const int KK = p2 ? 16 : 8;

  // ---- one-time: weight slice -> LDS, rotation swizzle pg = (c8 + 4*row) & C8m
  //      (read pattern below hits 64 distinct granules per wave access -> conflict-free)
  {
    const u16* Wsrc = p2 ? Wcat2 : Whh1;
    const int C8 = C8m + 1;
    for (int idx = tid; idx < 64 * C8; idx += 128) {
      int l = idx / C8, c8 = idx - l * C8;
      int gr = (l >> 4) * 256 + bh * 16 + (l & 15);
      int4 v = *(const int4*)(Wsrc + (size_t)gr * LD + c8 * 8);
      *(int4*)&wlds[l * LD + (((c8 + 4 * l) & C8m) * 8)] = v;
    }
  }
  float br4[4];
  {
    const float* bsrc = p2 ? b2sum : b1sum;
#pragma unroll
    for (int q = 0; q < 4; ++q) br4[q] = bsrc[q * 256 + hd];
  }
  __syncthreads();

  float creg[2][4] = {};
  u32* myflag = (p2 ? f2 : f1) + bm * 16 + bh;

#pragma unroll 1
  for (int s = 0; s < 119; ++s) {
    // ---- gate addend (X or bias) issued BEFORE the poll so it overlaps the wait ----
    const u16* Xb = nullptr;
    if (!p2 && s < 80)  Xb = X1t + (size_t)s * 262144;
    if (p2  && s >= 80) Xb = Xct + (size_t)(s - 80) * 262144;
    float ga[2][4][4];
    if (Xb) {
#pragma unroll
      for (int i = 0; i < 2; ++i)
#pragma unroll
        for (int r = 0; r < 4; ++r) {
          const int bat = bm * 64 + w * 32 + i * 16 + rq * 4 + r;
          const u16* xp = Xb + (size_t)bat * 1024;
#pragma unroll
          for (int q = 0; q < 4; ++q) ga[i][r][q] = b2f(xp[q * 256 + hd]);
        }
    } else {
#pragma unroll
      for (int i = 0; i < 2; ++i)
#pragma unroll
        for (int r = 0; r < 4; ++r)
#pragma unroll
          for (int q = 0; q < 4; ++q) ga[i][r][q] = br4[q];
    }
    // ---- watermark wait (wave 0 polls one or two 64B flag lines, read-only) ----
    if (w == 0 && (p2 || s > 0)) {
      const u32 tgt1 = p2 ? (u32)(s + 1) : (u32)s;
      const u32 tgt2 = (u32)s;
      while (true) {
        bool ok = true;
        if (lane < 16)
          ok = __hip_atomic_load(&f1[bm * 16 + lane], __ATOMIC_RELAXED,
                                 __HIP_MEMORY_SCOPE_AGENT) >= tgt1;
        else if (p2 && lane < 32)
          ok = __hip_atomic_load(&f2[bm * 16 + (lane - 16)], __ATOMIC_RELAXED,
                                 __HIP_MEMORY_SCOPE_AGENT) >= tgt2;
        if (__all(ok)) break;
        __builtin_amdgcn_s_sleep(4);
      }
    }
    __syncthreads();
    // ---- A fragments from history (sc1 loads bypass stale per-XCD L2) ----
    const u16* h1base = h1hist + (size_t)(p2 ? s + 1 : s) * 65536;
    const u16* h2base = h2hist + (size_t)s * 65536;
    s8v a[2][16];
#pragma unroll
    for (int i = 0; i < 2; ++i) {
      const int row = bm * 64 + w * 32 + i * 16 + fr;
#pragma unroll
      for (int kk = 0; kk < 16; ++kk) {
        if (kk < KK) {
          const u16* src = (kk < 8) ? (h1base + (size_t)row * 256 + kk * 32 + fk)
                                    : (h2base + (size_t)row * 256 + (kk - 8) * 32 + fk);
          union { u64 q[2]; s8v v; } u;
          u.q[0] = __hip_atomic_load((const u64*)src,     __ATOMIC_RELAXED,
                                     __HIP_MEMORY_SCOPE_AGENT);
          u.q[1] = __hip_atomic_load((const u64*)src + 1, __ATOMIC_RELAXED,
                                     __HIP_MEMORY_SCOPE_AGENT);
          a[i][kk] = u.v;
        }
      }
    }
    // ---- MFMAs (B from LDS, conflict-free rotation swizzle) ----
    f4v acc[2][4] = {};
#pragma unroll
    for (int kk = 0; kk < 16; ++kk) {
      if (kk < KK) {
#pragma unroll
        for (int q = 0; q < 4; ++q) {
          const int l = q * 16 + fr;
          s8v b = *(const s8v*)&wlds[l * LD + (((kk * 4 + fk8 + 4 * l) & C8m) * 8)];
#pragma unroll
          for (int i = 0; i < 2; ++i)
            acc[i][q] = __builtin_amdgcn_mfma_f32_16x16x32_bf16(a[i][kk], b, acc[i][q], 0, 0, 0);
        }
      }
    }
    // ---- cell update + h store (paired bf16 -> one u32 sc1 store per even lane) ----
    u16* hwbase = (p2 ? h2hist : h1hist) + (size_t)(s + 1) * 65536;
#pragma unroll
    for (int i = 0; i < 2; ++i) {
#pragma unroll
      for (int r = 0; r < 4; ++r) {
        const int bat = bm * 64 + w * 32 + i * 16 + rq * 4 + r;
        float g0 = acc[i][0][r] + ga[i][r][0], g1 = acc[i][1][r] + ga[i][r][1];
        float g2 = acc[i][2][r] + ga[i][r][2], g3 = acc[i][3][r] + ga[i][r][3];
        float cn = sigm(g1) * creg[i][r] + sigm(g0) * tanh_f(g2);
        float h = sigm(g3) * tanh_f(cn);
        creg[i][r] = cn;
        unsigned hb = f2b(h);
        unsigned ob = (unsigned)__shfl_xor((int)hb, 1);
        if ((fr & 1) == 0)
          __hip_atomic_store((u32*)(hwbase + (size_t)bat * 256 + hd), hb | (ob << 16),
                             __ATOMIC_RELAXED, __HIP_MEMORY_SCOPE_AGENT);
      }
    }
    // ---- publish watermark: drain stores, block-sync, single-writer flag ----
    asm volatile("s_waitcnt vmcnt(0)" ::: "memory");
    __syncthreads();
    if (tid == 0)
      __hip_atomic_store(myflag, (u32)(s + 1), __ATOMIC_RELAXED, __HIP_MEMORY_SCOPE_AGENT);
  }
}

// ---------------- combine per-tile LSE partials -> per-row NLL -------------------------
__global__ __launch_bounds__(256) void nll_combine(const float* __restrict__ pm,
                                                   const float* __restrict__ ps,
                                                   const float* __restrict__ tgtlog,
                                                   float* __restrict__ rowloss) {
  int row = blockIdx.x * 256 + threadIdx.x;
  if (row >= 9984) return;
  const float* pmr = pm + (size_t)row * 48;
  const float* psr = ps + (size_t)row * 48;
  float M = -1e30f;
#pragma unroll
  for (int t = 0; t < 48; ++t) M = fmaxf(M, pmr[t]);
  float S = 0.f;
#pragma unroll
  for (int t = 0; t < 48; ++t) S += psr[t] * __expf(pmr[t] - M);
  rowloss[row] = M + __logf(S) - tgtlog[row];
}

__global__ __launch_bounds__(256) void final_kernel(const float* __restrict__ rowloss,
                                                    float* __restrict__ out) {
  float s = 0.f;
  for (int n = threadIdx.x; n < 9984; n += 256) s += rowloss[n];
#pragma unroll
  for (int o = 1; o < 64; o <<= 1) s += __shfl_xor(s, o);
  __shared__ float sr[4];
  if ((threadIdx.x & 63) == 0) sr[threadIdx.x >> 6] = s;
  __syncthreads();
  if (threadIdx.x == 0) out[0] = (sr[0] + sr[1] + sr[2] + sr[3]) * (1.f / 256.f);
}

// ---------------------------------------------------------------------------------------
extern "C" void kernel_launch(void* const* d_in, const int* in_sizes, int n_in,
                              void* d_out, int out_size, void* d_ws, size_t ws_size,
                              hipStream_t stream) {
  const float* feat    = (const float*)d_in[0];
  const float* caption = (const float*)d_in[1];
  const float* coh     = (const float*)d_in[2];
  const float* W_ih1   = (const float*)d_in[3];
  const float* W_hh1   = (const float*)d_in[4];
  const float* b_ih1   = (const float*)d_in[5];
  const float* b_hh1   = (const float*)d_in[6];
  const float* W_ih2   = (const float*)d_in[7];
  const float* W_hh2   = (const float*)d_in[8];
  const float* b_ih2   = (const float*)d_in[9];
  const float* b_hh2   = (const float*)d_in[10];
  const float* W_out   = (const float*)d_in[11];
  const float* b_out   = (const float*)d_in[12];

  char* p = (char*)d_ws;
  auto take = [&](size_t bytes) { char* r = p; p += (bytes + 255) & ~(size_t)255; return r; };
  // persistent region
  u16* X1t    = (u16*)take(80ull * 256 * 1024 * 2);    // 41.9 MB, time-major
  u16* Xct    = (u16*)take(40ull * 256 * 1024 * 2);    // 21.0 MB, time-major
  u16* Wih1b  = (u16*)take(1024ull * 4096 * 2);
  u16* Whh1b  = (u16*)take(1024ull * 256 * 2);
  u16* Wih2ab = (u16*)take(1024ull * 256 * 2);
  u16* Wcat2b = (u16*)take(1024ull * 512 * 2);
  u16* Woutb  = (u16*)take((size_t)VOCP * 256 * 2);
  u16* h1hist = (u16*)take(120ull * 256 * 256 * 2);    // 15.7 MB
  u16* h2hist = (u16*)take(120ull * 256 * 256 * 2);    // 15.7 MB (slots 81.. = H2dec)
  float* b1sum = (float*)take(1024 * 4);
  float* b2sum = (float*)take(1024 * 4);
  float* boutp = (float*)take(VOCP * 4);
  int*   tgt   = (int*)take(9984 * 4);
  float* tgtlog = (float*)take(9984 * 4);
  float* pm    = (float*)take(9984ull * 48 * 4);
  float* ps    = (float*)take(9984ull * 48 * 4);
  float* rowloss = (float*)take(9984 * 4);
  u32* f1      = (u32*)take(256);                      // 64 flags
  u32* f2      = (u32*)take(256);
  // union region: {featb chunk (83.9 MB) + capb (5.2 MB)} only used before recurrence
  char* uni = p;
  u16* featb = (u16*)uni;
  u16* capb  = (u16*)(uni + 10240ull * 4096 * 2);

  // zero h slot 0 (both histories) and the watermark flags (f1,f2 contiguous)
  hipMemsetAsync(h1hist, 0, 256 * 256 * 2, stream);
  hipMemsetAsync(h2hist, 0, 256 * 256 * 2, stream);
  hipMemsetAsync(f1, 0, 512, stream);

  bias_setup<<<dim3(24), dim3(256), 0, stream>>>(b_ih1, b_hh1, b_ih2, b_hh2, b_out,
                                                 b1sum, b2sum, boutp);
  auto pack = [&](u16* dst, int dld, int doff, const float* src, int sld, int soff,
                  int Wc, int R, int Rs) {
    int tot = Wc * R;
    pack_bf16<<<dim3((tot + 255) / 256), dim3(256), 0, stream>>>(dst, dld, doff, src, sld, soff,
                                                                 Wc, R, Rs);
  };
  pack(Wih1b, 4096, 0, W_ih1, 4096, 0, 4096, 1024, 1024);
  pack(Whh1b, 256, 0, W_hh1, 256, 0, 256, 1024, 1024);
  pack(Wih2ab, 256, 0, W_ih2, 512, 0, 256, 1024, 1024);     // W_ih2[:, :256]
  pack(Wcat2b, 512, 0, W_ih2, 512, 256, 256, 1024, 1024);   // W_ih2[:, 256:]
  pack(Wcat2b, 512, 256, W_hh2, 256, 0, 256, 1024, 1024);   // W_hh2
  pack(Woutb, 256, 0, W_out, 256, 0, 256, VOCP, VOC);       // zero-padded rows

  argmax_kernel<<<dim3(39 * 256), dim3(256), 0, stream>>>(coh, tgt);

  // caption -> bf16, Xct = capb @ Wih2a^T + b2sum   (time-major epilogue)
  conv_f2b<<<dim3(2048), dim3(256), 0, stream>>>(caption, capb, 10240L * 256);
  gemm_bb<1><<<dim3(80, 4), dim3(256), 0, stream>>>(capb, Wih2ab, b2sum, Xct,
                                                    nullptr, nullptr, nullptr, 256, 0);

  // feat -> bf16 (2 chunks), X1t = featb @ Wih1^T + b1sum   (time-major epilogue)
  for (int c = 0; c < 2; ++c) {
    conv_f2b<<<dim3(2048), dim3(256), 0, stream>>>(feat + (size_t)c * 10240 * 4096, featb,
                                                   10240L * 4096);
    gemm_bb<0><<<dim3(80, 4), dim3(256), 0, stream>>>(featb, Wih1b, b1sum, X1t,
                                                      nullptr, nullptr, nullptr, 4096,
                                                      c * 10240);
  }

  // whole 119-step double-LSTM recurrence, barrier-free producer/consumer pipeline
  recur_kernel<<<dim3(128), dim3(128), 0, stream>>>(X1t, Xct, b1sum, b2sum,
                                                    Whh1b, Wcat2b, h1hist, h2hist, f1, f2);

  // logits GEMM with fused per-tile LSE partials + target-logit extraction
  gemm_bb<2><<<dim3(78, 24), dim3(256), 0, stream>>>(h2hist + 81ull * 65536, Woutb, boutp, pm,
                                                     ps, tgtlog, tgt, 256, 0);
  nll_combine<<<dim3(39), dim3(256), 0, stream>>>(pm, ps, tgtlog, rowloss);
  final_kernel<<<dim3(1), dim3(256), 0, stream>>>(rowloss, (float*)d_out);
}